// Round 5
// baseline (263.308 us; speedup 1.0000x reference)
//
#include <hip/hip_runtime.h>
#include <hip/hip_bf16.h>

// ContrastiveLoss (SimCLR InfoNCE): N=8192, D=1024, T=0.1
// nll[i] = -logit[i, (i+N/2)%N] + logsumexp_j(logit[i,j]), diag masked out
// logit = cos_sim / T; out = mean(nll)
//
// Identities:
//  - zn_i = z_i * sqrt(log2e/T)/||z_i||  =>  dot d = logit*log2e and
//    exp(logit-10) = 2^(d - 10*log2e)  -> raw v_exp_f32.
//  - logit in [-10,10] => FIXED-offset logsumexp; masked diagonal term is
//    exactly 0, handled only in the 32 diagonal supertiles.
//  - Gram symmetric: upper-triangular 256x256 supertiles only (528 of 1024);
//    off-diag tile (I,J) adds exp row-sums to rows of I, col-sums to rows of J.
//  - positive-pair logits = tile diagonals of supertiles (I, I+16), I<16.
//
// R5: FAT WAVE TILES. Wave tile 64x64 -> 128x128 (acc 8x8 floatx4 = 256
// VGPRs, 1 wave/SIMD): LDS bytes/MAC halves (0.0625 -> 0.031), per-phase
// compute grows to ~800 cyc of 64 independent MFMAs, so the distance-1
// global_load_lds prefetch covers load latency entirely in-wave. Block =
// 256x256 supertile, 4 waves 2x2, BK=32 double-buffered = exactly 64 KB LDS;
// epilogue reductions overlay sA. Grid 512, each block loops t, t+512 to
// balance 528 tiles onto 2 rounds of 256 CUs.

#define N_ROWS 8192
#define DIM    1024
#define SBM    256                     // supertile side
#define BK     32
#define NPHASE (DIM / BK)              // 32
#define NT     (N_ROWS / SBM)          // 32 supertiles per side
#define NTILES (NT * (NT + 1) / 2)     // 528
#define GRID   512
#define OFFS   14.4269504088896340f    // 10 * log2e
#define ROW_SCALE 3.7982825605f        // sqrt(10 * log2e)
#define LN2    0.6931471805599453f
#define LOGIT_MAX 10.0f

typedef __bf16 bf16x8 __attribute__((ext_vector_type(8)));
typedef float floatx4 __attribute__((ext_vector_type(4)));

__device__ __forceinline__ void async_copy16(const __hip_bfloat16* g, void* lds) {
  __builtin_amdgcn_global_load_lds(
      (const __attribute__((address_space(1))) void*)g,
      (__attribute__((address_space(3))) void*)lds, 16, 0, 0);
}

// ---------------- Kernel 1: row normalize (+ zero accumulators) -----------
__global__ __launch_bounds__(256) void normalize_kernel(
    const float* __restrict__ z, __hip_bfloat16* __restrict__ zn,
    float* __restrict__ sumexp, float* __restrict__ out) {
  const int tid = threadIdx.x, wave = tid >> 6, lane = tid & 63;
  const int row = blockIdx.x * 4 + wave;

  if (blockIdx.x < 8) ((float4*)sumexp)[blockIdx.x * 256 + tid] = float4{0, 0, 0, 0};
  if (blockIdx.x == 8 && tid == 0) out[0] = 0.0f;

  const float4* zr = (const float4*)(z + (size_t)row * DIM);
  float4 v[4];
  #pragma unroll
  for (int j = 0; j < 4; j++) v[j] = zr[lane + 64 * j];
  float ss = 0.0f;
  #pragma unroll
  for (int j = 0; j < 4; j++)
    ss += v[j].x * v[j].x + v[j].y * v[j].y + v[j].z * v[j].z + v[j].w * v[j].w;
  #pragma unroll
  for (int off = 32; off > 0; off >>= 1) ss += __shfl_xor(ss, off);
  const float scale = rsqrtf(ss) * ROW_SCALE;  // norms ~32 >> eps

  uint2* o = (uint2*)(zn + (size_t)row * DIM);
  #pragma unroll
  for (int j = 0; j < 4; j++) {
    __hip_bfloat16 ob[4];
    ob[0] = __float2bfloat16(v[j].x * scale);
    ob[1] = __float2bfloat16(v[j].y * scale);
    ob[2] = __float2bfloat16(v[j].z * scale);
    ob[3] = __float2bfloat16(v[j].w * scale);
    o[lane + 64 * j] = *(const uint2*)ob;
  }
}

// ---------------- Kernel 2: upper-tri GEMM + partial sum-exp --------------
__global__ __launch_bounds__(256, 1) void fused_gemm_lse(
    const __hip_bfloat16* __restrict__ zn, float* __restrict__ sumexp,
    float* __restrict__ pos) {
  __shared__ __hip_bfloat16 sA[2][SBM * BK];  // 2 x 16 KB
  __shared__ __hip_bfloat16 sB[2][SBM * BK];  // 2 x 16 KB  (total 64 KB)

  const int tid  = threadIdx.x;
  const int lane = tid & 63;
  const int wave = tid >> 6;
  const int quad = lane >> 4;
  const int l15  = lane & 15;
  const int waveM = wave >> 1;  // 0..1
  const int waveN = wave & 1;   // 0..1

  // static staging geometry: 256x32 tile = 1024 16B-chunks, 4 per thread.
  // XOR swizzle on the GLOBAL side: stored chunk (s&3) holds logical k-chunk
  // q = (s&3)^(r&3), so ds_read_b128 frag reads stay a bank-uniform
  // permutation while global_load_lds deposits at wave-uniform base+lane*16.
  int sr[4], sq[4], soff[4];
  #pragma unroll
  for (int i = 0; i < 4; i++) {
    const int sbase = i * 256 + wave * 64;  // wave-uniform chunk base
    const int s = sbase + lane;
    sr[i] = s >> 2;                  // tile row 0..255
    sq[i] = (s & 3) ^ (sr[i] & 3);   // logical k-chunk
    soff[i] = sbase * 16;            // LDS byte offset (wave-uniform)
  }

  for (int t = blockIdx.x; t < NTILES; t += GRID) {
    // decode upper-tri (I,J): row I starts at C(I) = NT*I - I*(I-1)/2
    int I = 0;
    while ((I + 1) * (2 * NT - I) / 2 <= t) ++I;
    const int J = I + (t - (NT * I - I * (I - 1) / 2));
    const int rowBase = I * SBM, colBase = J * SBM;

    const __hip_bfloat16* aP[4];
    const __hip_bfloat16* bP[4];
    #pragma unroll
    for (int i = 0; i < 4; i++) {
      aP[i] = zn + (size_t)(rowBase + sr[i]) * DIM + sq[i] * 8;
      bP[i] = zn + (size_t)(colBase + sr[i]) * DIM + sq[i] * 8;
    }
    auto stage = [&](int b) {
      char* baseA = (char*)sA[b];
      char* baseB = (char*)sB[b];
      #pragma unroll
      for (int i = 0; i < 4; i++) {
        async_copy16(aP[i], baseA + soff[i]);
        async_copy16(bP[i], baseB + soff[i]);
        aP[i] += BK;
        bP[i] += BK;
      }
    };

    floatx4 acc[8][8];
    #pragma unroll
    for (int mi = 0; mi < 8; mi++)
      #pragma unroll
      for (int ni = 0; ni < 8; ni++) acc[mi][ni] = {0.f, 0.f, 0.f, 0.f};

    __syncthreads();   // prior tile's LDS-overlay reads done before staging
    stage(0);

    const int ca = quad ^ (l15 & 3);   // frag chunk (row&3 == l15&3 here)
    for (int p = 0; p < NPHASE; ++p) {
      const int b = p & 1;
      __syncthreads();                 // drains phase p's loads
      if (p + 1 < NPHASE) stage(b ^ 1);  // prefetch next phase (async)

      bf16x8 a[8], bb[8];
      #pragma unroll
      for (int mi = 0; mi < 8; mi++)
        a[mi] = ((const bf16x8*)sA[b])[(waveM * 128 + mi * 16 + l15) * 4 + ca];
      #pragma unroll
      for (int ni = 0; ni < 8; ni++)
        bb[ni] = ((const bf16x8*)sB[b])[(waveN * 128 + ni * 16 + l15) * 4 + ca];
      #pragma unroll
      for (int mi = 0; mi < 8; mi++)
        #pragma unroll
        for (int ni = 0; ni < 8; ni++)
          acc[mi][ni] = __builtin_amdgcn_mfma_f32_16x16x32_bf16(
              a[mi], bb[ni], acc[mi][ni], 0, 0, 0);
    }

    // ---- epilogue ----
    // C/D layout (16x16): col = lane&15, row = quad*4 + reg  [m89]
    // local row = waveM*128 + mi*16 + quad*4 + r ; col = waveN*128 + ni*16 + l15
    const bool diagBlk = (I == J);

    if (J == I + NT / 2 && waveM == waveN) {  // positive-pair supertile
      #pragma unroll
      for (int mi = 0; mi < 8; mi++)
        #pragma unroll
        for (int r = 0; r < 4; r++)
          if (l15 == quad * 4 + r)
            pos[rowBase + waveM * 128 + mi * 16 + l15] = acc[mi][mi][r];
    }

    float rsum[8][4], csum[8];
    #pragma unroll
    for (int mi = 0; mi < 8; mi++)
      #pragma unroll
      for (int r = 0; r < 4; r++) rsum[mi][r] = 0.0f;
    #pragma unroll
    for (int ni = 0; ni < 8; ni++) csum[ni] = 0.0f;

    if (diagBlk) {
      #pragma unroll
      for (int mi = 0; mi < 8; mi++)
        #pragma unroll
        for (int ni = 0; ni < 8; ni++) {
          const bool dtile = (waveM == waveN) && (mi == ni);
          #pragma unroll
          for (int r = 0; r < 4; r++) {
            float e = exp2f(acc[mi][ni][r] - OFFS);
            if (dtile && l15 == quad * 4 + r) e = 0.0f;  // masked diagonal
            rsum[mi][r] += e;
          }
        }
    } else {
      #pragma unroll
      for (int mi = 0; mi < 8; mi++)
        #pragma unroll
        for (int ni = 0; ni < 8; ni++)
          #pragma unroll
          for (int r = 0; r < 4; r++) {
            const float e = exp2f(acc[mi][ni][r] - OFFS);
            rsum[mi][r] += e;
            csum[ni]    += e;
          }
    }

    // overlay reductions into sA (frag reads finished; barrier first)
    float* rowRed = (float*)sA;          // [2][256]
    float* colRed = ((float*)sA) + 512;  // [2][256]
    __syncthreads();

    #pragma unroll
    for (int mi = 0; mi < 8; mi++)
      #pragma unroll
      for (int r = 0; r < 4; r++) {
        float v = rsum[mi][r];
        v += __shfl_xor(v, 1);
        v += __shfl_xor(v, 2);
        v += __shfl_xor(v, 4);
        v += __shfl_xor(v, 8);
        if (l15 == 0)
          rowRed[waveN * 256 + waveM * 128 + mi * 16 + quad * 4 + r] = v;
      }
    if (!diagBlk) {
      #pragma unroll
      for (int ni = 0; ni < 8; ni++) {
        float v = csum[ni];
        v += __shfl_xor(v, 16);
        v += __shfl_xor(v, 32);
        if (quad == 0)
          colRed[waveM * 256 + waveN * 128 + ni * 16 + l15] = v;
      }
    }
    __syncthreads();

    atomicAdd(&sumexp[rowBase + tid], rowRed[tid] + rowRed[256 + tid]);
    if (!diagBlk)
      atomicAdd(&sumexp[colBase + tid], colRed[tid] + colRed[256 + tid]);
  }
}

// ---------------- Kernel 3: mean NLL --------------------------------------
__global__ __launch_bounds__(256) void finalize_kernel(
    const float* __restrict__ sumexp, const float* __restrict__ pos,
    float* __restrict__ out) {
  const int tid = threadIdx.x;
  const int row = blockIdx.x * 256 + tid;
  // pos holds d = logit*log2e for rows [0,4096); pos[i+4096] == pos[i]
  float local = -(pos[row & (N_ROWS / 2 - 1)] * LN2) + LOGIT_MAX + logf(sumexp[row]);
  #pragma unroll
  for (int off = 32; off > 0; off >>= 1) local += __shfl_xor(local, off);
  __shared__ float red[4];
  const int wave = tid >> 6, lane = tid & 63;
  if (lane == 0) red[wave] = local;
  __syncthreads();
  if (tid == 0)
    atomicAdd(out, (red[0] + red[1] + red[2] + red[3]) * (1.0f / N_ROWS));
}

extern "C" void kernel_launch(void* const* d_in, const int* in_sizes, int n_in,
                              void* d_out, int out_size, void* d_ws, size_t ws_size,
                              hipStream_t stream) {
  const float* z = (const float*)d_in[0];
  float* out = (float*)d_out;

  char* ws = (char*)d_ws;
  __hip_bfloat16* zn = (__hip_bfloat16*)ws;                  // 16 MB
  float* sumexp = (float*)(ws + (size_t)N_ROWS * DIM * 2);   // 32 KB
  float* pos    = sumexp + N_ROWS;                           // 16 KB (4096)

  normalize_kernel<<<N_ROWS / 4, 256, 0, stream>>>(z, zn, sumexp, out);
  fused_gemm_lse<<<GRID, 256, 0, stream>>>(zn, sumexp, pos);
  finalize_kernel<<<N_ROWS / 256, 256, 0, stream>>>(sumexp, pos, out);
}